// Round 4
// baseline (788.567 us; speedup 1.0000x reference)
//
#include <hip/hip_runtime.h>
#include <hip/hip_cooperative_groups.h>
#include <math.h>

namespace cg = cooperative_groups;

#define B    128
#define CTRL 1024
#define NN   4096
#define MM   64
#define OD   70     // M + 6
#define NC   8      // n-chunks per batch
#define CHUNK (NN / NC)   // 512 rows per block

// DPP-based 16-lane group sum (pure VALU, no LDS pipe).
#define DPP_ADD(v, ctrl)                                                        \
    do {                                                                        \
        int _t = __builtin_amdgcn_update_dpp(0, __float_as_int(v), (ctrl),      \
                                             0xF, 0xF, true);                   \
        (v) += __int_as_float(_t);                                              \
    } while (0)

__device__ inline float sum16(float v) {
    DPP_ADD(v, 0xB1);    // quad_perm xor1
    DPP_ADD(v, 0x4E);    // quad_perm xor2
    DPP_ADD(v, 0x141);   // row_half_mirror
    DPP_ADD(v, 0x140);   // row_mirror
    return v;
}

// One cooperative kernel, 4 phases separated by grid.sync():
//   A: o = emb @ fc_w.T + fc_b ; zero r/zsum/psum
//   B: ev = exp(beta * cos_sim(k, mem[b,n,:])) ; partial-sum -> zsum[b]
//   C: w_g -> 3-tap shift -> wt^gamma (wp kept in LDS) ; partial -> psum[b]
//   D: w = wp/psum -> w_out ; r = sum_n w*mem -> atomic r_out
__global__ __launch_bounds__(256, 4) void k_fused(
    const float* __restrict__ emb, const float* __restrict__ w_prev,
    const float* __restrict__ mem, const float* __restrict__ fc_w,
    const float* __restrict__ fc_b,
    float* __restrict__ r_out, float* __restrict__ w_out,
    float* __restrict__ o, float* __restrict__ ev_buf,
    float* __restrict__ zsum, float* __restrict__ psum)
{
    cg::grid_group grid = cg::this_grid();
    int c = blockIdx.x;   // 0..7  (n-chunk)
    int b = blockIdx.y;   // 0..127
    int t = threadIdx.x;  // 0..255

    __shared__ float sh[CHUNK + 2];            // k (B) / wg then wp (C,D)
    __shared__ __align__(16) float4 acc_sh[256];
    __shared__ float red[4];
    __shared__ float kb[2];

    // ---------------- phase A ----------------
    if (c == 0 && t < MM) r_out[(size_t)b * MM + t] = 0.f;
    if (c == 1 && t == 0) { zsum[b] = 0.f; psum[b] = 0.f; }

    {
        const float4* e4 = (const float4*)(emb + (size_t)b * CTRL);
        float4 ev = e4[t];
        for (int j = c; j < OD; j += NC) {
            const float4* w4 = (const float4*)(fc_w + (size_t)j * CTRL);
            float4 wv = w4[t];
            float s = ev.x * wv.x + ev.y * wv.y + ev.z * wv.z + ev.w * wv.w;
            for (int off = 32; off; off >>= 1) s += __shfl_xor(s, off);
            if ((t & 63) == 0) red[t >> 6] = s;
            __syncthreads();
            if (t == 0) o[(size_t)b * OD + j] = red[0] + red[1] + red[2] + red[3] + fc_b[j];
            __syncthreads();
        }
    }
    __threadfence();
    grid.sync();

    // ---------------- phase B ----------------
    if (t < MM) sh[t] = o[(size_t)b * OD + t];
    __syncthreads();
    if (t == 0) {
        float ss = 0.f;
        for (int i = 0; i < MM; ++i) ss += sh[i] * sh[i];
        kb[0] = sqrtf(ss);
        float x = o[(size_t)b * OD + MM];
        kb[1] = fmaxf(x, 0.f) + log1pf(expf(-fabsf(x)));   // softplus -> beta
    }
    __syncthreads();
    float knorm = kb[0], beta = kb[1];

    int lane16 = t & 15;
    int rgrp   = t >> 4;
    float4 k4 = ((const float4*)sh)[lane16];
    int n0 = c * CHUNK;

    float evsum = 0.f;
    #pragma unroll 8
    for (int i = 0; i < 32; ++i) {
        int n = n0 + rgrp + i * 16;
        const float4* m4 = (const float4*)(mem + ((size_t)b * NN + n) * MM);
        float4 v = m4[lane16];
        float dot = v.x * k4.x + v.y * k4.y + v.z * k4.z + v.w * k4.w;
        float ssq = v.x * v.x + v.y * v.y + v.z * v.z + v.w * v.w;
        dot = sum16(dot);
        ssq = sum16(ssq);
        if (lane16 == 0) {
            // no max-shift needed: |beta*sim| <= ~5, exp fp32-safe
            float e = __expf(beta * dot / (knorm * sqrtf(ssq) + 1e-16f));
            ev_buf[(size_t)b * NN + n] = e;
            evsum += e;
        }
    }
    for (int off = 32; off; off >>= 1) evsum += __shfl_xor(evsum, off);
    __syncthreads();
    if ((t & 63) == 0) red[t >> 6] = evsum;
    __syncthreads();
    if (t == 0) atomicAdd(&zsum[b], red[0] + red[1] + red[2] + red[3]);
    __threadfence();
    grid.sync();

    // ---------------- phase C ----------------
    float g, s0, s1, s2, gamma;
    {
        const float* ob = o + (size_t)b * OD;
        g = 1.f / (1.f + __expf(-ob[MM + 1]));
        float a0 = ob[MM + 2], a1 = ob[MM + 3], a2 = ob[MM + 4];
        float mx = fmaxf(a0, fmaxf(a1, a2));
        float e0 = __expf(a0 - mx), e1 = __expf(a1 - mx), e2 = __expf(a2 - mx);
        float es = e0 + e1 + e2;
        float x = ob[MM + 5];
        gamma = 1.f + fmaxf(x, 0.f) + log1pf(__expf(-fabsf(x)));
        s0 = e0 / es; s1 = e1 / es; s2 = e2 / es;
    }
    float invsum = 1.f / zsum[b];

    // wg for n0-1 .. n0+CHUNK (514 values, circular) into sh
    for (int idx = t; idx < CHUNK + 2; idx += 256) {
        int n = (n0 - 1 + idx + NN) & (NN - 1);
        size_t off = (size_t)b * NN + n;
        sh[idx] = g * ev_buf[off] * invsum + (1.f - g) * w_prev[off];
    }
    __syncthreads();

    float myp0, myp1, ps;
    {
        float wt0 = s0 * sh[t]       + s1 * sh[t + 1]   + s2 * sh[t + 2];
        float wt1 = s0 * sh[t + 256] + s1 * sh[t + 257] + s2 * sh[t + 258];
        myp0 = __powf(wt0, gamma);
        myp1 = __powf(wt1, gamma);
        ps = myp0 + myp1;
    }
    for (int off = 32; off; off >>= 1) ps += __shfl_xor(ps, off);
    __syncthreads();                     // all wg reads done before overwrite
    if ((t & 63) == 0) red[t >> 6] = ps;
    sh[t]       = myp0;                  // sh now holds wp for this chunk
    sh[t + 256] = myp1;
    __syncthreads();
    if (t == 0) atomicAdd(&psum[b], red[0] + red[1] + red[2] + red[3]);
    __threadfence();
    grid.sync();

    // ---------------- phase D ----------------
    float invz = 1.f / (psum[b] + 1e-16f);
    w_out[(size_t)b * NN + n0 + t]       = sh[t] * invz;
    w_out[(size_t)b * NN + n0 + t + 256] = sh[t + 256] * invz;

    float4 acc = {0.f, 0.f, 0.f, 0.f};
    const float4* base = (const float4*)(mem + ((size_t)b * NN + n0) * MM);
    #pragma unroll 8
    for (int i = 0; i < 32; ++i) {
        int row = rgrp + i * 16;
        float4 v = base[(size_t)row * 16 + lane16];
        float wv = sh[row] * invz;
        acc.x += wv * v.x; acc.y += wv * v.y;
        acc.z += wv * v.z; acc.w += wv * v.w;
    }
    acc_sh[t] = acc;
    __syncthreads();
    if (t < 16) {
        float4 s = {0.f, 0.f, 0.f, 0.f};
        for (int j = 0; j < 16; ++j) {
            float4 v = acc_sh[t + j * 16];
            s.x += v.x; s.y += v.y; s.z += v.z; s.w += v.w;
        }
        float* rb = r_out + (size_t)b * MM + t * 4;
        atomicAdd(rb + 0, s.x);
        atomicAdd(rb + 1, s.y);
        atomicAdd(rb + 2, s.z);
        atomicAdd(rb + 3, s.w);
    }
}

// ---------------------------------------------------------------------------
extern "C" void kernel_launch(void* const* d_in, const int* in_sizes, int n_in,
                              void* d_out, int out_size, void* d_ws, size_t ws_size,
                              hipStream_t stream) {
    const float* emb    = (const float*)d_in[0];   // B x CTRL
    const float* w_prev = (const float*)d_in[1];   // B x N
    const float* mem    = (const float*)d_in[2];   // B x N x M
    const float* fc_w   = (const float*)d_in[3];   // OD x CTRL
    const float* fc_b   = (const float*)d_in[4];   // OD

    float* r_out = (float*)d_out;                  // B x M
    float* w_out = r_out + (size_t)B * MM;         // B x N

    // workspace layout (fp32)
    float* ev   = (float*)d_ws;                    // B x N  (exp(beta*sim))
    float* o    = ev + (size_t)B * NN;             // B x OD
    float* zsum = o + (size_t)B * OD;              // B
    float* psum = zsum + B;                        // B

    void* args[] = { (void*)&emb, (void*)&w_prev, (void*)&mem, (void*)&fc_w,
                     (void*)&fc_b, (void*)&r_out, (void*)&w_out, (void*)&o,
                     (void*)&ev, (void*)&zsum, (void*)&psum };

    hipLaunchCooperativeKernel((const void*)k_fused, dim3(NC, B), dim3(256),
                               args, 0, stream);
}

// Round 5
// 234.979 us; speedup vs baseline: 3.3559x; 3.3559x over previous
//
#include <hip/hip_runtime.h>
#include <math.h>

#define B    128
#define CTRL 1024
#define NN   4096
#define MM   64
#define OD   70     // M + 6
#define NC   8      // n-chunks per batch
#define CHUNK 512   // NN / NC

// DPP-based 16-lane group sum (pure VALU, no LDS pipe).
#define DPP_ADD(v, ctrl)                                                        \
    do {                                                                        \
        int _t = __builtin_amdgcn_update_dpp(0, __float_as_int(v), (ctrl),      \
                                             0xF, 0xF, true);                   \
        (v) += __int_as_float(_t);                                              \
    } while (0)

__device__ inline float sum16(float v) {
    DPP_ADD(v, 0xB1);    // quad_perm xor1
    DPP_ADD(v, 0x4E);    // quad_perm xor2
    DPP_ADD(v, 0x141);   // row_half_mirror
    DPP_ADD(v, 0x140);   // row_mirror
    return v;
}

// ---------------- kernel 1: o = emb @ fc_w.T + fc_b ; zero accumulators -----
__global__ void k_ctrl(const float* __restrict__ emb,
                       const float* __restrict__ fc_w,
                       const float* __restrict__ fc_b,
                       float* __restrict__ o,
                       float* __restrict__ zsum,
                       float* __restrict__ psum,
                       float* __restrict__ rnum) {
    int j = blockIdx.x;       // 0..OD-1
    int b = blockIdx.y;       // 0..B-1
    int t = threadIdx.x;      // 0..255

    if (j == 0 && t < MM) rnum[(size_t)b * MM + t] = 0.f;
    if (j == 1 && t == 0) { zsum[b] = 0.f; psum[b] = 0.f; }

    const float4* e = (const float4*)(emb + (size_t)b * CTRL);
    const float4* w = (const float4*)(fc_w + (size_t)j * CTRL);
    float4 ev = e[t];
    float4 wv = w[t];
    float s = ev.x * wv.x + ev.y * wv.y + ev.z * wv.z + ev.w * wv.w;
    for (int off = 32; off; off >>= 1) s += __shfl_xor(s, off);
    __shared__ float red[4];
    if ((t & 63) == 0) red[t >> 6] = s;
    __syncthreads();
    if (t == 0)
        o[(size_t)b * OD + j] = red[0] + red[1] + red[2] + red[3] + fc_b[j];
}

// ---------------- kernel 2: ev[b,n] = exp(beta*cos_sim) ; zsum[b] += ... ----
// grid (NC, B), block 256. 16 lanes per row; 512 rows per block.
__global__ void k_sim(const float* __restrict__ mem,
                      const float* __restrict__ o,
                      float* __restrict__ ev_buf,
                      float* __restrict__ zsum) {
    int b  = blockIdx.y;
    int n0 = blockIdx.x * CHUNK;
    int t  = threadIdx.x;

    __shared__ __align__(16) float k_sh[MM];
    __shared__ float kb[2];   // knorm, beta
    __shared__ float red[4];

    if (t < MM) k_sh[t] = o[(size_t)b * OD + t];
    __syncthreads();
    if (t == 0) {
        float ss = 0.f;
        for (int i = 0; i < MM; ++i) ss += k_sh[i] * k_sh[i];
        kb[0] = sqrtf(ss);
        float x = o[(size_t)b * OD + MM];
        kb[1] = fmaxf(x, 0.f) + log1pf(expf(-fabsf(x)));   // softplus -> beta
    }
    __syncthreads();
    float knorm = kb[0], beta = kb[1];

    int lane16 = t & 15;
    int rgrp   = t >> 4;
    float4 k4 = ((const float4*)k_sh)[lane16];

    float evsum = 0.f;
    #pragma unroll 8
    for (int i = 0; i < 32; ++i) {
        int n = n0 + rgrp + i * 16;
        const float4* m4 = (const float4*)(mem + ((size_t)b * NN + n) * MM);
        float4 v = m4[lane16];
        float dot = v.x * k4.x + v.y * k4.y + v.z * k4.z + v.w * k4.w;
        float ssq = v.x * v.x + v.y * v.y + v.z * v.z + v.w * v.w;
        dot = sum16(dot);
        ssq = sum16(ssq);
        if (lane16 == 0) {
            // no max-shift: |beta*sim| <= ~5, exp fp32-safe; softmax shift-invariant
            float e = __expf(beta * dot / (knorm * sqrtf(ssq) + 1e-16f));
            ev_buf[(size_t)b * NN + n] = e;
            evsum += e;
        }
    }
    for (int off = 32; off; off >>= 1) evsum += __shfl_xor(evsum, off);
    if ((t & 63) == 0) red[t >> 6] = evsum;
    __syncthreads();
    if (t == 0) atomicAdd(&zsum[b], red[0] + red[1] + red[2] + red[3]);
}

// ---------------- kernel 3: wp = wt^gamma (LDS) ; psum += ; rnum += sweep ---
// grid (NC, B), block 256. powf overlaps the L3-served second memory sweep.
__global__ void k_wr(const float* __restrict__ mem,
                     const float* __restrict__ w_prev,
                     const float* __restrict__ o,
                     const float* __restrict__ ev_buf,
                     const float* __restrict__ zsum,
                     float* __restrict__ wp_buf,
                     float* __restrict__ psum,
                     float* __restrict__ rnum) {
    int c = blockIdx.x;
    int b = blockIdx.y;
    int t = threadIdx.x;
    int n0 = c * CHUNK;

    __shared__ float wg_sh[CHUNK + 2];
    __shared__ float wp_sh[CHUNK];
    __shared__ __align__(16) float4 acc_sh[256];
    __shared__ float red[4];

    // scalars (every thread, broadcast loads)
    const float* ob = o + (size_t)b * OD;
    float g  = 1.f / (1.f + __expf(-ob[MM + 1]));
    float a0 = ob[MM + 2], a1 = ob[MM + 3], a2 = ob[MM + 4];
    float mx = fmaxf(a0, fmaxf(a1, a2));
    float e0 = __expf(a0 - mx), e1 = __expf(a1 - mx), e2 = __expf(a2 - mx);
    float es = e0 + e1 + e2;
    float s0 = e0 / es, s1 = e1 / es, s2 = e2 / es;
    float xg = ob[MM + 5];
    float gamma = 1.f + fmaxf(xg, 0.f) + log1pf(__expf(-fabsf(xg)));
    float invsum = 1.f / zsum[b];

    size_t boff = (size_t)b * NN;
    for (int idx = t; idx < CHUNK + 2; idx += 256) {
        int n = (n0 - 1 + idx) & (NN - 1);
        wg_sh[idx] = g * ev_buf[boff + n] * invsum + (1.f - g) * w_prev[boff + n];
    }
    __syncthreads();

    float wt0 = s0 * wg_sh[t]       + s1 * wg_sh[t + 1]   + s2 * wg_sh[t + 2];
    float wt1 = s0 * wg_sh[t + 256] + s1 * wg_sh[t + 257] + s2 * wg_sh[t + 258];
    float wp0 = __powf(wt0, gamma);
    float wp1 = __powf(wt1, gamma);
    wp_sh[t]       = wp0;
    wp_sh[t + 256] = wp1;
    wp_buf[boff + n0 + t]       = wp0;
    wp_buf[boff + n0 + t + 256] = wp1;

    float ps = wp0 + wp1;
    for (int off = 32; off; off >>= 1) ps += __shfl_xor(ps, off);
    if ((t & 63) == 0) red[t >> 6] = ps;
    __syncthreads();
    if (t == 0) atomicAdd(&psum[b], red[0] + red[1] + red[2] + red[3]);

    // ---- sweep 2: rnum[b,:] += sum_n wp[n] * mem[b,n,:] (L3-resident) ----
    int m4 = t & 15;
    int rg = t >> 4;
    float4 acc = {0.f, 0.f, 0.f, 0.f};
    const float4* base = (const float4*)(mem + (boff + n0) * MM);
    #pragma unroll 8
    for (int i = 0; i < 32; ++i) {
        int row = rg + i * 16;
        float4 v = base[(size_t)row * 16 + m4];
        float wv = wp_sh[row];
        acc.x += wv * v.x; acc.y += wv * v.y;
        acc.z += wv * v.z; acc.w += wv * v.w;
    }
    acc_sh[t] = acc;
    __syncthreads();
    if (t < 16) {
        float4 s = {0.f, 0.f, 0.f, 0.f};
        for (int j = 0; j < 16; ++j) {
            float4 v = acc_sh[t + j * 16];
            s.x += v.x; s.y += v.y; s.z += v.z; s.w += v.w;
        }
        float* rb = rnum + (size_t)b * MM + t * 4;
        atomicAdd(rb + 0, s.x);
        atomicAdd(rb + 1, s.y);
        atomicAdd(rb + 2, s.z);
        atomicAdd(rb + 3, s.w);
    }
}

// ---------------- kernel 4: normalize w and r by psum+eps -------------------
__global__ void k_norm(const float* __restrict__ wp_buf,
                       const float* __restrict__ psum,
                       const float* __restrict__ rnum,
                       float* __restrict__ r_out,
                       float* __restrict__ w_out) {
    int c = blockIdx.x;
    int b = blockIdx.y;
    int t = threadIdx.x;
    float invz = 1.f / (psum[b] + 1e-16f);
    size_t boff = (size_t)b * NN + (size_t)c * CHUNK;
    w_out[boff + t]       = wp_buf[boff + t] * invz;
    w_out[boff + t + 256] = wp_buf[boff + t + 256] * invz;
    if (c == 0 && t < MM)
        r_out[(size_t)b * MM + t] = rnum[(size_t)b * MM + t] * invz;
}

// ---------------------------------------------------------------------------
extern "C" void kernel_launch(void* const* d_in, const int* in_sizes, int n_in,
                              void* d_out, int out_size, void* d_ws, size_t ws_size,
                              hipStream_t stream) {
    const float* emb    = (const float*)d_in[0];   // B x CTRL
    const float* w_prev = (const float*)d_in[1];   // B x N
    const float* mem    = (const float*)d_in[2];   // B x N x M
    const float* fc_w   = (const float*)d_in[3];   // OD x CTRL
    const float* fc_b   = (const float*)d_in[4];   // OD

    float* r_out = (float*)d_out;                  // B x M
    float* w_out = r_out + (size_t)B * MM;         // B x N

    // workspace layout (fp32)
    float* ev   = (float*)d_ws;                    // B x N
    float* wp   = ev + (size_t)B * NN;             // B x N
    float* o    = wp + (size_t)B * NN;             // B x OD
    float* zsum = o + (size_t)B * OD;              // B
    float* psum = zsum + B;                        // B
    float* rnum = psum + B;                        // B x M

    k_ctrl<<<dim3(OD, B), 256, 0, stream>>>(emb, fc_w, fc_b, o, zsum, psum, rnum);
    k_sim <<<dim3(NC, B), 256, 0, stream>>>(mem, o, ev, zsum);
    k_wr  <<<dim3(NC, B), 256, 0, stream>>>(mem, w_prev, o, ev, zsum, wp, psum, rnum);
    k_norm<<<dim3(NC, B), 256, 0, stream>>>(wp, psum, rnum, r_out, w_out);
}